// Round 6
// baseline (1015.236 us; speedup 1.0000x reference)
//
#include <hip/hip_runtime.h>
#include <hip/hip_bf16.h>

// Problem constants
#define NB    65536      // batch rows
#define KDIM  1024       // reduction dim for all projections
#define NDIM  1024       // output dim per projection

// 256x256 8-phase GEMM geometry
#define BM 256
#define BN 256
#define BK 64
#define NT (KDIM / BK)   // 16 K-tiles

typedef float f32x4 __attribute__((ext_vector_type(4)));
typedef short short8 __attribute__((ext_vector_type(8)));
typedef unsigned short ushort8v __attribute__((ext_vector_type(8)));

static __device__ __forceinline__ unsigned short f2bf(float f) {
    union { float f; unsigned u; } v; v.f = f;
    unsigned r = v.u + 0x7FFFu + ((v.u >> 16) & 1u);
    return (unsigned short)(r >> 16);
}
static __device__ __forceinline__ float bf2f(unsigned short h) {
    union { unsigned u; float f; } v; v.u = ((unsigned)h) << 16;
    return v.f;
}

// async global->LDS, 16B per lane. LDS dest = wave-uniform base + lane*16.
static __device__ __forceinline__ void gload16(const unsigned short* g, unsigned short* l) {
    __builtin_amdgcn_global_load_lds(
        (const __attribute__((address_space(1))) unsigned int*)g,
        (__attribute__((address_space(3))) unsigned int*)l, 16, 0, 0);
}

// ---------------------------------------------------------------------------
// fp32 -> bf16 convert, grid-stride, 4 elems/thread/iter
// ---------------------------------------------------------------------------
__global__ __launch_bounds__(256) void f32_to_bf16_k(
    const float* __restrict__ s, unsigned short* __restrict__ d, int n4)
{
    const int stride = gridDim.x * 256;
    for (int i = blockIdx.x * 256 + threadIdx.x; i < n4; i += stride) {
        float4 v = reinterpret_cast<const float4*>(s)[i];
        ushort4 o;
        o.x = f2bf(v.x); o.y = f2bf(v.y); o.z = f2bf(v.z); o.w = f2bf(v.w);
        reinterpret_cast<ushort4*>(d)[i] = o;
    }
}

// ---------------------------------------------------------------------------
// 256x256 8-phase GEMM: C[M,N] = A[M,K] @ W[N,K]^T (+bias)
// 512 threads = 8 waves (2 Mwaves x 4 Nwaves); per-wave output 128x64.
// LDS: fragment-ordered 1KB blocks (zero-conflict ds_read_b128), 128 KB dbuf.
// Phase split: quadrant = (m-half) x (k-half); per phase (8,4,8,4) ds_reads,
// 16 MFMA. Sync per phase: {reads; stage; [vmcnt(8)]; barrier; MFMA; barrier}
// with vmcnt(8) ONLY at phases 2 and 4 (m201 cadence). NO sched_barrier, NO
// explicit lgkmcnt -- compiler emits fine-grained counted lgkm waits (m141:
// order-pinning defeats the scheduler; m97: compiler lgkm is near-optimal).
//
// Guard proof (stage s-index = 2-load units; prologue s=1..6 stages
// t0A0,t0B0,t0A1,t0B1,t1A0,t1B0; then t.p1:(t+1)A1 s=7+4t, p2:(t+1)B1,
// p3:(t+2)A0, p4:(t+2)B0):
//   t.p1/p2 read t.A0 (s=1+4t), t.B0 (s=2+4t); latest prior guard =
//     (t-1).p4 vmcnt(8) after s=6+4t -> guarantees <= 2+4t  OK
//   t.p3/p4 read t.A1 (s=3+4t), t.B1 (s=4+4t); guard = t.p2 vmcnt(8)
//     after s=8+4t -> guarantees <= 4+4t  OK
//   prologue vmcnt(8) after s=6 -> <=2 covers group0.p1  OK
// LDS overwrite safety: every region's overwrite is issued >=1 full barrier
// after its last read completed (reads complete before consuming MFMA, which
// precedes that phase's trailing barrier). Tail stages clamp to tile NT-1
// (junk but cadence-preserving, race-free by the same argument).
// ---------------------------------------------------------------------------
template<int OUT_F32>
__global__ __launch_bounds__(512, 2) void gemm256(
    const unsigned short* __restrict__ Ap, const unsigned short* __restrict__ Wp,
    const float* __restrict__ bias, void* __restrict__ Cptr)
{
    constexpr int N = NDIM;
    constexpr int GN = NDIM / BN;            // 4 col tiles
    __shared__ alignas(16) unsigned short lds[2][2][32][512];  // [buf][A|B][blk=f*2+ks][1KB]

    const int t    = threadIdx.x;
    const int lane = t & 63;
    const int wid  = t >> 6;                 // 0..7
    const int wm   = wid >> 2;               // 0..1  (128 rows each)
    const int wn   = wid & 3;                // 0..3  (64 cols each)

    // XCD-chunked swizzle (nwg = 1024, % 8 == 0)
    const int nwg  = gridDim.x;
    const int cpx  = nwg >> 3;
    const int orig = blockIdx.x;
    const int wgid = (orig & 7) * cpx + (orig >> 3);
    const int bn0  = (wgid & (GN - 1)) * BN;
    const int bm0  = (wgid / GN) * BM;

    // per-lane fragment offset within a block's 16-row x 32-col source region
    const size_t aoff = (size_t)(lane & 15) * KDIM + (lane >> 4) * 8;

#define FENCE_ asm volatile("" ::: "memory")
#define BAR_   do { FENCE_; __builtin_amdgcn_s_barrier(); FENCE_; } while (0)
#define VMBAR_ do { asm volatile("s_waitcnt vmcnt(8)" ::: "memory");            \
                    __builtin_amdgcn_s_barrier(); FENCE_; } while (0)

#define LDA_(BUF, MI, KS) \
    (*reinterpret_cast<const short8*>(&lds[BUF][0][(wm * 8 + (MI)) * 2 + (KS)][lane * 8]))
#define LDB_(BUF, NI, KS) \
    (*reinterpret_cast<const short8*>(&lds[BUF][1][(wn * 4 + (NI)) * 2 + (KS)][lane * 8]))

    // stage one 16KB chunk (tile TAU, A|B, k-half KS) into buffer slot SLOT
#define STAGE_(TAU, SLOT, AB, KS) do {                                          \
        int _tc = (TAU) < NT ? (TAU) : NT - 1;  /* tail clamp: keep cadence */  \
        const unsigned short* _b = (AB) ? Wp : Ap;                              \
        int _r0 = (AB) ? bn0 : bm0;                                             \
        _Pragma("unroll")                                                       \
        for (int _j = 0; _j < 2; ++_j) {                                        \
            int _f = wid * 2 + _j;                                              \
            gload16(_b + (size_t)(_r0 + _f * 16) * KDIM + _tc * BK + (KS) * 32 + aoff, \
                    &lds[SLOT][AB][_f * 2 + (KS)][0]);                          \
        }                                                                       \
    } while (0)

#define MFMA_(ACCB, AF) do { _Pragma("unroll")                                  \
    for (int mi = 0; mi < 4; ++mi) {                                            \
        acc[(ACCB) + mi][0] = __builtin_amdgcn_mfma_f32_16x16x32_bf16(AF[mi], bq0, acc[(ACCB) + mi][0], 0, 0, 0); \
        acc[(ACCB) + mi][1] = __builtin_amdgcn_mfma_f32_16x16x32_bf16(AF[mi], bq1, acc[(ACCB) + mi][1], 0, 0, 0); \
        acc[(ACCB) + mi][2] = __builtin_amdgcn_mfma_f32_16x16x32_bf16(AF[mi], bq2, acc[(ACCB) + mi][2], 0, 0, 0); \
        acc[(ACCB) + mi][3] = __builtin_amdgcn_mfma_f32_16x16x32_bf16(AF[mi], bq3, acc[(ACCB) + mi][3], 0, 0, 0); \
    } } while (0)

#define GROUP_(BUF, OBUF, TT) do {                                              \
        /* p1: ks0, m-lo (8 reads) */                                           \
        _Pragma("unroll")                                                       \
        for (int mi = 0; mi < 4; ++mi) afA[mi] = LDA_(BUF, mi, 0);              \
        bq0 = LDB_(BUF, 0, 0); bq1 = LDB_(BUF, 1, 0);                           \
        bq2 = LDB_(BUF, 2, 0); bq3 = LDB_(BUF, 3, 0);                           \
        STAGE_((TT) + 1, OBUF, 0, 1);                                           \
        BAR_;                                                                   \
        __builtin_amdgcn_s_setprio(1); MFMA_(0, afA); __builtin_amdgcn_s_setprio(0); \
        BAR_;                                                                   \
        /* p2: ks0, m-hi (4 reads) */                                           \
        _Pragma("unroll")                                                       \
        for (int mi = 0; mi < 4; ++mi) afB[mi] = LDA_(BUF, 4 + mi, 0);          \
        STAGE_((TT) + 1, OBUF, 1, 1);                                           \
        VMBAR_;                                                                 \
        __builtin_amdgcn_s_setprio(1); MFMA_(4, afB); __builtin_amdgcn_s_setprio(0); \
        BAR_;                                                                   \
        /* p3: ks1, m-lo (8 reads) */                                           \
        _Pragma("unroll")                                                       \
        for (int mi = 0; mi < 4; ++mi) afA[mi] = LDA_(BUF, mi, 1);              \
        bq0 = LDB_(BUF, 0, 1); bq1 = LDB_(BUF, 1, 1);                           \
        bq2 = LDB_(BUF, 2, 1); bq3 = LDB_(BUF, 3, 1);                           \
        STAGE_((TT) + 2, BUF, 0, 0);                                            \
        BAR_;                                                                   \
        __builtin_amdgcn_s_setprio(1); MFMA_(0, afA); __builtin_amdgcn_s_setprio(0); \
        BAR_;                                                                   \
        /* p4: ks1, m-hi (4 reads) */                                           \
        _Pragma("unroll")                                                       \
        for (int mi = 0; mi < 4; ++mi) afB[mi] = LDA_(BUF, 4 + mi, 1);          \
        STAGE_((TT) + 2, BUF, 1, 0);                                            \
        VMBAR_;                                                                 \
        __builtin_amdgcn_s_setprio(1); MFMA_(4, afB); __builtin_amdgcn_s_setprio(0); \
        BAR_;                                                                   \
    } while (0)

    f32x4 acc[8][4];
#pragma unroll
    for (int mi = 0; mi < 8; ++mi)
#pragma unroll
        for (int ni = 0; ni < 4; ++ni)
            acc[mi][ni] = (f32x4){0.f, 0.f, 0.f, 0.f};

    short8 afA[4], afB[4], bq0, bq1, bq2, bq3;

    // prologue: tile0 fully + tile1 k-half0 (6 stages, 12 loads)
    STAGE_(0, 0, 0, 0); STAGE_(0, 0, 1, 0);
    STAGE_(0, 0, 0, 1); STAGE_(0, 0, 1, 1);
    STAGE_(1, 1, 0, 0); STAGE_(1, 1, 1, 0);
    VMBAR_;   // guarantees tile0 ks0 (s<=2) landed for group0.p1

#pragma unroll 1
    for (int tt = 0; tt < NT; tt += 2) {
        GROUP_(0, 1, tt);
        GROUP_(1, 0, tt + 1);
    }

    // drain junk tail gloads before endpgm (LDS may be reallocated to the
    // next workgroup; in-flight LDS-DMA writes would corrupt it)
    asm volatile("s_waitcnt vmcnt(0)" ::: "memory");

    // epilogue: D row = (lane>>4)*4 + r, col = lane&15  [m89-verified]
    const int crow = (lane >> 4) * 4;
    const int ccol = lane & 15;
    if (OUT_F32) {
        float* Cf = (float*)Cptr;
        float bv[4];
#pragma unroll
        for (int ni = 0; ni < 4; ++ni)
            bv[ni] = bias[bn0 + wn * 64 + ni * 16 + ccol];
#pragma unroll
        for (int mi = 0; mi < 8; ++mi)
#pragma unroll
            for (int ni = 0; ni < 4; ++ni) {
                size_t base = (size_t)(bm0 + wm * 128 + mi * 16 + crow) * N
                            + (bn0 + wn * 64 + ni * 16 + ccol);
#pragma unroll
                for (int r = 0; r < 4; ++r)
                    Cf[base + (size_t)r * N] = acc[mi][ni][r] + bv[ni];
            }
    } else {
        unsigned short* Cb = (unsigned short*)Cptr;
#pragma unroll
        for (int mi = 0; mi < 8; ++mi)
#pragma unroll
            for (int ni = 0; ni < 4; ++ni) {
                size_t base = (size_t)(bm0 + wm * 128 + mi * 16 + crow) * N
                            + (bn0 + wn * 64 + ni * 16 + ccol);
#pragma unroll
                for (int r = 0; r < 4; ++r)
                    Cb[base + (size_t)r * N] = f2bf(acc[mi][ni][r]);
            }
    }
#undef FENCE_
#undef BAR_
#undef VMBAR_
#undef LDA_
#undef LDB_
#undef STAGE_
#undef MFMA_
#undef GROUP_
}

// ---------------------------------------------------------------------------
// Per-row attention (unchanged, verified): 1 wave/row, 4 waves/block.
// ---------------------------------------------------------------------------
__global__ __launch_bounds__(256) void attn_k(
    const unsigned short* __restrict__ Qb, const unsigned short* __restrict__ Kb,
    const unsigned short* __restrict__ Vb, unsigned short* __restrict__ Fb)
{
    __shared__ alignas(16) unsigned short KL[4][1024];
    __shared__ alignas(16) unsigned short VL[4][1024];
    const int t = threadIdx.x;
    const int lane = t & 63;
    const int wid = t >> 6;
    const size_t row = (size_t)blockIdx.x * 4 + wid;
    const size_t base = row * 1024;
    const int off = lane * 16;

    ushort8v q0 = *reinterpret_cast<const ushort8v*>(&Qb[base + off]);
    ushort8v q1 = *reinterpret_cast<const ushort8v*>(&Qb[base + off + 8]);
    float qf[16];
#pragma unroll
    for (int j = 0; j < 8; ++j) { qf[j] = bf2f(q0[j]); qf[8 + j] = bf2f(q1[j]); }

    *reinterpret_cast<ushort8v*>(&KL[wid][off])     = *reinterpret_cast<const ushort8v*>(&Kb[base + off]);
    *reinterpret_cast<ushort8v*>(&KL[wid][off + 8]) = *reinterpret_cast<const ushort8v*>(&Kb[base + off + 8]);
    *reinterpret_cast<ushort8v*>(&VL[wid][off])     = *reinterpret_cast<const ushort8v*>(&Vb[base + off]);
    *reinterpret_cast<ushort8v*>(&VL[wid][off + 8]) = *reinterpret_cast<const ushort8v*>(&Vb[base + off + 8]);
    __syncthreads();

    const int sub = lane & 3;
    float s[16];
#pragma unroll
    for (int g = 0; g < 16; ++g) {
        const ushort8v k0 = *reinterpret_cast<const ushort8v*>(&KL[wid][g * 64 + sub * 16]);
        const ushort8v k1 = *reinterpret_cast<const ushort8v*>(&KL[wid][g * 64 + sub * 16 + 8]);
        float acc = 0.f;
#pragma unroll
        for (int j = 0; j < 8; ++j)
            acc += qf[j] * bf2f(k0[j]) + qf[8 + j] * bf2f(k1[j]);
        s[g] = acc;
    }
#pragma unroll
    for (int m = 1; m <= 2; m <<= 1)
#pragma unroll
        for (int g = 0; g < 16; ++g)
            s[g] += __shfl_xor(s[g], m, 64);

    float mx = s[0];
#pragma unroll
    for (int g = 1; g < 16; ++g) mx = fmaxf(mx, s[g]);
    float p[16], denom = 0.f;
#pragma unroll
    for (int g = 0; g < 16; ++g) {
        p[g] = __expf((s[g] - mx) * 0.125f);
        denom += p[g];
    }
    float inv = 1.f / denom;

    float f[16];
#pragma unroll
    for (int j = 0; j < 16; ++j) f[j] = 0.f;
#pragma unroll
    for (int g = 0; g < 16; ++g) {
        float pg = p[g] * inv;
        const ushort8v v0 = *reinterpret_cast<const ushort8v*>(&VL[wid][g * 64 + sub * 16]);
        const ushort8v v1 = *reinterpret_cast<const ushort8v*>(&VL[wid][g * 64 + sub * 16 + 8]);
#pragma unroll
        for (int j = 0; j < 8; ++j) {
            f[j]     += pg * bf2f(v0[j]);
            f[8 + j] += pg * bf2f(v1[j]);
        }
    }
    ushort8v o0, o1;
#pragma unroll
    for (int j = 0; j < 8; ++j) { o0[j] = f2bf(f[j]); o1[j] = f2bf(f[8 + j]); }
    *reinterpret_cast<ushort8v*>(&Fb[base + off])     = o0;
    *reinterpret_cast<ushort8v*>(&Fb[base + off + 8]) = o1;
}

// ---------------------------------------------------------------------------
extern "C" void kernel_launch(void* const* d_in, const int* in_sizes, int n_in,
                              void* d_out, int out_size, void* d_ws, size_t ws_size,
                              hipStream_t stream)
{
    (void)in_sizes; (void)n_in; (void)out_size; (void)ws_size;
    const float* latent = (const float*)d_in[0];
    const float* cond   = (const float*)d_in[1];
    const float* Wq     = (const float*)d_in[2];
    const float* Wk     = (const float*)d_in[3];
    const float* Wv     = (const float*)d_in[4];
    const float* Wout   = (const float*)d_in[5];
    const float* bout   = (const float*)d_in[6];
    float* out = (float*)d_out;

    char* ws = (char*)d_ws;
    const size_t MB = 1ull << 20;
    unsigned short* wqb = (unsigned short*)(ws + 0 * MB);
    unsigned short* wkb = (unsigned short*)(ws + 2 * MB);
    unsigned short* wvb = (unsigned short*)(ws + 4 * MB);
    unsigned short* wob = (unsigned short*)(ws + 6 * MB);
    unsigned short* Qb  = (unsigned short*)(ws + 8 * MB);              // 128 MB, becomes feats
    unsigned short* Kbf = (unsigned short*)(ws + 8 * MB + 128 * MB);   // 128 MB
    unsigned short* Vbf = (unsigned short*)(ws + 8 * MB + 256 * MB);   // 128 MB
    unsigned short* Lb  = (unsigned short*)(ws + 8 * MB + 384 * MB);   // 128 MB latent bf16
    unsigned short* Cb  = (unsigned short*)(ws + 8 * MB + 512 * MB);   // 128 MB cond bf16

    const int wn4 = (KDIM * NDIM) / 4;
    f32_to_bf16_k<<<1024, 256, 0, stream>>>(Wq,   wqb, wn4);
    f32_to_bf16_k<<<1024, 256, 0, stream>>>(Wk,   wkb, wn4);
    f32_to_bf16_k<<<1024, 256, 0, stream>>>(Wv,   wvb, wn4);
    f32_to_bf16_k<<<1024, 256, 0, stream>>>(Wout, wob, wn4);

    const int an4 = (NB * KDIM) / 4;
    f32_to_bf16_k<<<4096, 256, 0, stream>>>(latent, Lb, an4);
    f32_to_bf16_k<<<4096, 256, 0, stream>>>(cond,   Cb, an4);

    const int nblk = (NB / BM) * (NDIM / BN);   // 256 * 4 = 1024
    gemm256<0><<<nblk, 512, 0, stream>>>(Lb, wqb, nullptr, Qb);
    gemm256<0><<<nblk, 512, 0, stream>>>(Cb, wkb, nullptr, Kbf);
    gemm256<0><<<nblk, 512, 0, stream>>>(Cb, wvb, nullptr, Vbf);

    attn_k<<<NB / 4, 256, 0, stream>>>(Qb, Kbf, Vbf, Qb);

    gemm256<1><<<nblk, 512, 0, stream>>>(Qb, wob, bout, out);
}